// Round 19
// baseline (159.036 us; speedup 1.0000x reference)
//
#include <hip/hip_runtime.h>
#include <hip/hip_cooperative_groups.h>

namespace cg = cooperative_groups;

#define CDIM 128
#define HDIM 128
#define LIM  40960   // nodes cached in phase-E LDS (x4 B = 163840 B)

typedef short bf16x8 __attribute__((ext_vector_type(8)));
typedef float f32x16 __attribute__((ext_vector_type(16)));

// fp32 -> bf16 bits, round-to-nearest-even
static __device__ __forceinline__ short f2bf(float f) {
    union { float f; unsigned u; } v; v.f = f;
    unsigned r = v.u + 0x7FFFu + ((v.u >> 16) & 1u);
    return (short)(r >> 16);
}
static __device__ __forceinline__ unsigned pack2(float a, float b) {
    return (unsigned)(unsigned short)f2bf(a) | ((unsigned)(unsigned short)f2bf(b) << 16);
}

// Phase-N layout (34816 B) and phase-E layout (163840 B) share one allocation.
union SharedU {
    struct { short wf[16384]; float cv[512]; } n;
    unsigned lt[LIM];
};

// ---------------------------------------------------------------------------
// Fused cooperative kernel: 256 blocks x 1024 thr, 1 block/CU (LDS-limited).
// Phase N: blocks < NB run the R17 node body (waves 0-7 compute; all 16 waves
//          share the W transforms). Blocks >= NB pre-stream casts [0, CS).
// grid.sync(); Phase E: R18 edge body (identical 16-wave shape), cast writes
// guarded u >= CS. tab via device-scope atomicExch (R12-proven XCD visibility).
// NO min-waves launch-bounds arg: VGPR cap 128 > ~110 needed (R13/R15 lesson).
// ---------------------------------------------------------------------------
__global__ __launch_bounds__(1024) void fused_kernel(
    const float* __restrict__ x,
    const int* __restrict__ eip, const int* __restrict__ ein,
    const float* __restrict__ W1, const float* __restrict__ b1,
    const float* __restrict__ W2, const float* __restrict__ b2,
    const float* __restrict__ We, const float* __restrict__ be_p,
    unsigned* __restrict__ tab, float* __restrict__ out, int N, int E)
{
    __shared__ SharedU s;
    const int tid = threadIdx.x;
    const int blk = blockIdx.x;
    const int NB  = (N + 255) >> 8;              // node blocks (196)
    const int l   = tid & 63;
    const int col = l & 31;
    const int hi  = l >> 5;
    const int U   = E >> 2;                      // 4-edge units
    const int NC  = (int)gridDim.x - NB;         // pure-cast blocks (60)
    const int CS  = (int)(((long long)U * NC) / (int)gridDim.x);  // cast split

    if (blk < NB) {
        // ================= phase N: node tile (256 nodes) =================
        const int node = blk * 256 + ((tid >> 6) & 7) * 32 + col;  // tid<512 only

        // ---- x loads issued first (latency hides under W1 transform) ----
        float4 xr[16];
        if (tid < 512) {
            const int nclamp = (node < N) ? node : (N - 1);
            const float* xb = &x[(size_t)nclamp * CDIM + hi * 8];
#pragma unroll
            for (int ks = 0; ks < 8; ks++) {
                xr[2 * ks]     = *(const float4*)(xb + ks * 16);
                xr[2 * ks + 1] = *(const float4*)(xb + ks * 16 + 4);
            }
        }

        // ---- W1 transform: ALL 1024 threads, 2 iters ----
#pragma unroll
        for (int t = 0; t < 2; t++) {
            int rem = t * 1024 + tid;            // 0..2047
            int lv = rem & 63, ks = (rem >> 6) & 7, ct = rem >> 9;
            int k0 = ks * 16 + 8 * (lv >> 5);
            int n  = ct * 32 + (lv & 31);
            bf16x8 wvv;
#pragma unroll
            for (int j = 0; j < 8; j++) wvv[j] = f2bf(W1[(k0 + j) * HDIM + n]);
            *(bf16x8*)&s.n.wf[rem * 8] = wvv;
        }
        if (tid < 512)
            s.n.cv[tid] = (tid < 128) ? b1[tid]
                        : (tid < 256) ? b2[tid - 128] : We[tid - 256];

        bf16x8 af[8];
        if (tid < 512) {
#pragma unroll
            for (int ks = 0; ks < 8; ks++) {
                float4 v0 = xr[2 * ks], v1 = xr[2 * ks + 1];
                af[ks][0] = f2bf(v0.x); af[ks][1] = f2bf(v0.y);
                af[ks][2] = f2bf(v0.z); af[ks][3] = f2bf(v0.w);
                af[ks][4] = f2bf(v1.x); af[ks][5] = f2bf(v1.y);
                af[ks][6] = f2bf(v1.z); af[ks][7] = f2bf(v1.w);
            }
        }
        __syncthreads();   // wf(W1) + cv ready

        const f32x16 zz = {0.f,0.f,0.f,0.f,0.f,0.f,0.f,0.f,0.f,0.f,0.f,0.f,0.f,0.f,0.f,0.f};
        f32x16 acc[4];
        unsigned P[4][4][2], Q[4][4][2];
        if (tid < 512) {
            // ---- layer 1 ----
#pragma unroll
            for (int ct = 0; ct < 4; ct++) acc[ct] = zz;
#pragma unroll
            for (int ks = 0; ks < 8; ks++) {
#pragma unroll
                for (int ct = 0; ct < 4; ct++) {
                    bf16x8 wfrag = *(const bf16x8*)&s.n.wf[((ct * 8 + ks) * 64 + l) * 8];
                    acc[ct] = __builtin_amdgcn_mfma_f32_32x32x16_bf16(wfrag, af[ks], acc[ct], 0, 0, 0);
                }
            }
            // ---- h1 pack ----
#pragma unroll
            for (int ct = 0; ct < 4; ct++) {
#pragma unroll
                for (int g = 0; g < 4; g++) {
                    float4 bv = *(const float4*)&s.n.cv[32 * ct + 8 * g + 4 * hi];
                    float h0  = fmaxf(acc[ct][4 * g + 0] + bv.x, 0.f);
                    float h1v = fmaxf(acc[ct][4 * g + 1] + bv.y, 0.f);
                    float h2v = fmaxf(acc[ct][4 * g + 2] + bv.z, 0.f);
                    float h3v = fmaxf(acc[ct][4 * g + 3] + bv.w, 0.f);
                    P[ct][g][0] = pack2(h0, h1v);
                    P[ct][g][1] = pack2(h2v, h3v);
                }
            }
#pragma unroll
            for (int ct = 0; ct < 4; ct++)
#pragma unroll
                for (int g = 0; g < 4; g++)
#pragma unroll
                    for (int p = 0; p < 2; p++)
                        Q[ct][g][p] = (unsigned)__shfl_xor((int)P[ct][g][p], 32, 64);
        }
        __syncthreads();   // all waves done reading wf(W1)

        // ---- W2 transform: ALL 1024 threads ----
#pragma unroll
        for (int t = 0; t < 2; t++) {
            int rem = t * 1024 + tid;
            int lv = rem & 63, ks = (rem >> 6) & 7, ct = rem >> 9;
            int k0 = ks * 16 + 8 * (lv >> 5);
            int n  = ct * 32 + (lv & 31);
            bf16x8 wvv;
#pragma unroll
            for (int j = 0; j < 8; j++) wvv[j] = f2bf(W2[(k0 + j) * HDIM + n]);
            *(bf16x8*)&s.n.wf[rem * 8] = wvv;
        }
        __syncthreads();   // wf(W2) ready

        if (tid < 512) {
            // ---- layer 2 ----
            f32x16 acc2[4];
#pragma unroll
            for (int ct = 0; ct < 4; ct++) acc2[ct] = zz;
#pragma unroll
            for (int ks2 = 0; ks2 < 8; ks2++) {
                const int c  = ks2 >> 1;
                const int s2 = (ks2 & 1) * 2;
                union { bf16x8 v; unsigned u[4]; } bb;
                bb.u[0] = hi ? Q[c][s2 + 1][0] : P[c][s2][0];
                bb.u[1] = hi ? Q[c][s2 + 1][1] : P[c][s2][1];
                bb.u[2] = hi ? P[c][s2 + 1][0] : Q[c][s2][0];
                bb.u[3] = hi ? P[c][s2 + 1][1] : Q[c][s2][1];
#pragma unroll
                for (int ct = 0; ct < 4; ct++) {
                    bf16x8 wfrag = *(const bf16x8*)&s.n.wf[((ct * 8 + ks2) * 64 + l) * 8];
                    acc2[ct] = __builtin_amdgcn_mfma_f32_32x32x16_bf16(wfrag, bb.v, acc2[ct], 0, 0, 0);
                }
            }
            // ---- epilogue ----
            float pq = 0.f, pk = 0.f;
#pragma unroll
            for (int ct = 0; ct < 4; ct++) {
#pragma unroll
                for (int g = 0; g < 4; g++) {
                    float4 b2v = *(const float4*)&s.n.cv[128 + 32 * ct + 8 * g + 4 * hi];
                    float4 wqv = *(const float4*)&s.n.cv[256 + 32 * ct + 8 * g + 4 * hi];
                    float4 wkv = *(const float4*)&s.n.cv[384 + 32 * ct + 8 * g + 4 * hi];
                    const float* b2a = (const float*)&b2v;
                    const float* wqa = (const float*)&wqv;
                    const float* wka = (const float*)&wkv;
#pragma unroll
                    for (int i = 0; i < 4; i++) {
                        float hv = fmaxf(acc2[ct][4 * g + i] + b2a[i], 0.f);
                        pq = fmaf(hv, wqa[i], pq);
                        pk = fmaf(hv, wka[i], pk);
                    }
                }
            }
            pq += __shfl_xor(pq, 32, 64);
            pk += __shfl_xor(pk, 32, 64);
            if (hi == 0 && node < N) atomicExch(&tab[node], pack2(pq, pk));
        }
    } else {
        // ========== pure-cast block: stream casts for i in [0, CS) ==========
        const int rank = blk - NB;
        const int4* ein4 = (const int4*)ein;
        float4* o4 = (float4*)out;
        for (int i = rank * 1024 + tid; i < CS; i += NC * 1024) {
            int4 v = ein4[i];
            o4[2 * U + i] = make_float4((float)v.x, (float)v.y, (float)v.z, (float)v.w);
            int4 w = ein4[U + i];
            o4[3 * U + i] = make_float4((float)w.x, (float)w.y, (float)w.z, (float)w.w);
        }
    }

    __threadfence();
    cg::this_grid().sync();   // all tab writes device-visible

    // ================= phase E: edge scores (R18 body) =================
    const int wv = tid >> 6, ln = tid & 63;
    const int chunk = (U + (int)gridDim.x - 1) / (int)gridDim.x;
    const int ustart = blk * chunk;
    const int uend = min(U, ustart + chunk);

    const int4* eip4 = (const int4*)eip;
    const int4* ein4 = (const int4*)ein;
    float4* out4 = (float4*)out;

    const int u0 = ustart + tid, u1 = u0 + 1024;
    const bool v0 = u0 < uend, v1 = u1 < uend;

    // ---- step 1: index preloads (oldest in vmcnt FIFO) ----
    int4 ns0 = {0,0,0,0}, nd0 = {0,0,0,0}, ns1 = {0,0,0,0}, nd1 = {0,0,0,0};
    int4 ps0 = {0,0,0,0}, pd0 = {0,0,0,0};
    if (v0) { ns0 = ein4[u0]; nd0 = ein4[U + u0]; ps0 = eip4[u0]; pd0 = eip4[U + u0]; }
    if (v1) { ns1 = ein4[u1]; nd1 = ein4[U + u1]; }
    __builtin_amdgcn_sched_barrier(0);

    // ---- step 2: staging DMA: 10240 uint4, 16 waves x 10 iters ----
    const uint4* tg4 = (const uint4*)tab;
#pragma unroll
    for (int t = 0; t < LIM / 4 / 1024; t++) {
        int c = (t * 16 + wv) * 64;
        __builtin_amdgcn_global_load_lds(
            (const __attribute__((address_space(1))) void*)(tg4 + c + ln),
            (__attribute__((address_space(3))) void*)((char*)s.lt + (size_t)c * 16),
            16, 0, 0);
    }
    __builtin_amdgcn_sched_barrier(0);

    // ---- step 3: cast outputs (only u >= CS; [0,CS) pre-streamed) ----
    if (v0 && u0 >= CS) {
        out4[2 * U + u0] = make_float4((float)ns0.x, (float)ns0.y, (float)ns0.z, (float)ns0.w);
        out4[3 * U + u0] = make_float4((float)nd0.x, (float)nd0.y, (float)nd0.z, (float)nd0.w);
    }
    if (v1 && u1 >= CS) {
        out4[2 * U + u1] = make_float4((float)ns1.x, (float)ns1.y, (float)ns1.z, (float)ns1.w);
        out4[3 * U + u1] = make_float4((float)nd1.x, (float)nd1.y, (float)nd1.z, (float)nd1.w);
    }
    __syncthreads();   // drains DMA (vmcnt 0) + makes lt visible

    const float be = be_p[0];
#define GATHER(i) ((i) < LIM ? s.lt[i] : tab[i])
#define SCORE(us, ud) (__uint_as_float((us) << 16) + __uint_as_float((ud) & 0xFFFF0000u) + be)

    int4 ps1 = {0,0,0,0}, pd1 = {0,0,0,0};
    if (v1) { ps1 = eip4[u1]; pd1 = eip4[U + u1]; }

    if (v0) {
        unsigned a0 = GATHER(ps0.x), a1 = GATHER(ps0.y), a2 = GATHER(ps0.z), a3 = GATHER(ps0.w);
        unsigned b0 = GATHER(pd0.x), b1v = GATHER(pd0.y), b2v = GATHER(pd0.z), b3 = GATHER(pd0.w);
        out4[u0] = make_float4(SCORE(a0,b0), SCORE(a1,b1v), SCORE(a2,b2v), SCORE(a3,b3));
        unsigned c0 = GATHER(ns0.x), c1 = GATHER(ns0.y), c2 = GATHER(ns0.z), c3 = GATHER(ns0.w);
        unsigned d0 = GATHER(nd0.x), d1 = GATHER(nd0.y), d2 = GATHER(nd0.z), d3 = GATHER(nd0.w);
        out4[U + u0] = make_float4(SCORE(c0,d0), SCORE(c1,d1), SCORE(c2,d2), SCORE(c3,d3));
    }
    if (v1) {
        unsigned a0 = GATHER(ps1.x), a1 = GATHER(ps1.y), a2 = GATHER(ps1.z), a3 = GATHER(ps1.w);
        unsigned b0 = GATHER(pd1.x), b1v = GATHER(pd1.y), b2v = GATHER(pd1.z), b3 = GATHER(pd1.w);
        out4[u1] = make_float4(SCORE(a0,b0), SCORE(a1,b1v), SCORE(a2,b2v), SCORE(a3,b3));
        unsigned c0 = GATHER(ns1.x), c1 = GATHER(ns1.y), c2 = GATHER(ns1.z), c3 = GATHER(ns1.w);
        unsigned d0 = GATHER(nd1.x), d1 = GATHER(nd1.y), d2 = GATHER(nd1.z), d3 = GATHER(nd1.w);
        out4[U + u1] = make_float4(SCORE(c0,d0), SCORE(c1,d1), SCORE(c2,d2), SCORE(c3,d3));
    }
#undef GATHER
#undef SCORE
}

extern "C" void kernel_launch(void* const* d_in, const int* in_sizes, int n_in,
                              void* d_out, int out_size, void* d_ws, size_t ws_size,
                              hipStream_t stream) {
    const float* x   = (const float*)d_in[0];
    const int*   eip = (const int*)d_in[1];
    const int*   ein = (const int*)d_in[2];
    // d_in[3] = batch (unused)
    const float* W1  = (const float*)d_in[4];
    const float* b1  = (const float*)d_in[5];
    const float* W2  = (const float*)d_in[6];
    const float* b2  = (const float*)d_in[7];
    const float* We  = (const float*)d_in[8];
    const float* be  = (const float*)d_in[9];

    int N = in_sizes[0] / CDIM;
    int E = in_sizes[1] / 2;

    unsigned* tab = (unsigned*)d_ws;   // N*4 B packed bf16x2 score table
    float* outp = (float*)d_out;

    void* args[] = { (void*)&x, (void*)&eip, (void*)&ein,
                     (void*)&W1, (void*)&b1, (void*)&W2, (void*)&b2,
                     (void*)&We, (void*)&be, (void*)&tab, (void*)&outp,
                     (void*)&N, (void*)&E };
    hipLaunchCooperativeKernel((const void*)fused_kernel, dim3(256), dim3(1024),
                               args, 0, stream);
}

// Round 20
// 113.789 us; speedup vs baseline: 1.3976x; 1.3976x over previous
//
#include <hip/hip_runtime.h>
#include <hip/hip_cooperative_groups.h>

namespace cg = cooperative_groups;

#define CDIM 128
#define HDIM 128
#define LIM  40960   // nodes cached in phase-E LDS (x4 B = 163840 B)

typedef short bf16x8 __attribute__((ext_vector_type(8)));
typedef float f32x16 __attribute__((ext_vector_type(16)));

// fp32 -> bf16 bits, round-to-nearest-even
static __device__ __forceinline__ short f2bf(float f) {
    union { float f; unsigned u; } v; v.f = f;
    unsigned r = v.u + 0x7FFFu + ((v.u >> 16) & 1u);
    return (short)(r >> 16);
}
static __device__ __forceinline__ unsigned pack2(float a, float b) {
    return (unsigned)(unsigned short)f2bf(a) | ((unsigned)(unsigned short)f2bf(b) << 16);
}

// Phase-N layout (34816 B) and phase-E layout (163840 B) share one allocation.
union SharedU {
    struct { short wf[16384]; float cv[512]; } n;
    unsigned lt[LIM];
};

// ---------------------------------------------------------------------------
// Fused cooperative kernel: 256 blocks x 512 thr (1024-thr blocks get VGPR
// clamped to 64 by hipcc -> spills; 512-thr proven >= 88 VGPR in R6-R18).
// Phase N: blocks < NB run the R17 node body; blocks >= NB pre-stream casts
// [0, CS). grid.sync(); phase E: R14's 512-thr edge body, casts guarded
// u >= CS. tab via device-scope atomicExch (R12-proven XCD visibility).
// ---------------------------------------------------------------------------
__global__ __launch_bounds__(512) void fused_kernel(
    const float* __restrict__ x,
    const int* __restrict__ eip, const int* __restrict__ ein,
    const float* __restrict__ W1, const float* __restrict__ b1,
    const float* __restrict__ W2, const float* __restrict__ b2,
    const float* __restrict__ We, const float* __restrict__ be_p,
    unsigned* __restrict__ tab, float* __restrict__ out, int N, int E)
{
    __shared__ SharedU s;
    const int tid = threadIdx.x;
    const int blk = blockIdx.x;
    const int NB  = (N + 255) >> 8;              // node blocks (196)
    const int l   = tid & 63;
    const int col = l & 31;
    const int hi  = l >> 5;
    const int U   = E >> 2;                      // 4-edge units
    const int NC  = (int)gridDim.x - NB;         // pure-cast blocks (60)
    const int CS  = (int)(((long long)U * NC) / (int)gridDim.x);  // cast split

    if (blk < NB) {
        // ================= phase N: node tile (256 nodes, R17 body) =======
        const int node = blk * 256 + (tid >> 6) * 32 + col;

        // ---- x loads issued first (latency hides under W1 transform) ----
        const int nclamp = (node < N) ? node : (N - 1);
        const float* xb = &x[(size_t)nclamp * CDIM + hi * 8];
        float4 xr[16];
#pragma unroll
        for (int ks = 0; ks < 8; ks++) {
            xr[2 * ks]     = *(const float4*)(xb + ks * 16);
            xr[2 * ks + 1] = *(const float4*)(xb + ks * 16 + 4);
        }

        // ---- W1 transform: dest-linear, 4 iters/thread ----
#pragma unroll
        for (int t = 0; t < 4; t++) {
            int rem = t * 512 + tid;             // 0..2047
            int lv = rem & 63, ks = (rem >> 6) & 7, ct = rem >> 9;
            int k0 = ks * 16 + 8 * (lv >> 5);
            int n  = ct * 32 + (lv & 31);
            bf16x8 wvv;
#pragma unroll
            for (int j = 0; j < 8; j++) wvv[j] = f2bf(W1[(k0 + j) * HDIM + n]);
            *(bf16x8*)&s.n.wf[rem * 8] = wvv;
        }
        s.n.cv[tid] = (tid < 128) ? b1[tid]
                    : (tid < 256) ? b2[tid - 128] : We[tid - 256];

        bf16x8 af[8];
#pragma unroll
        for (int ks = 0; ks < 8; ks++) {
            float4 v0 = xr[2 * ks], v1 = xr[2 * ks + 1];
            af[ks][0] = f2bf(v0.x); af[ks][1] = f2bf(v0.y);
            af[ks][2] = f2bf(v0.z); af[ks][3] = f2bf(v0.w);
            af[ks][4] = f2bf(v1.x); af[ks][5] = f2bf(v1.y);
            af[ks][6] = f2bf(v1.z); af[ks][7] = f2bf(v1.w);
        }
        __syncthreads();   // wf(W1) + cv ready

        const f32x16 zz = {0.f,0.f,0.f,0.f,0.f,0.f,0.f,0.f,0.f,0.f,0.f,0.f,0.f,0.f,0.f,0.f};

        // ---- layer 1 ----
        f32x16 acc[4];
#pragma unroll
        for (int ct = 0; ct < 4; ct++) acc[ct] = zz;
#pragma unroll
        for (int ks = 0; ks < 8; ks++) {
#pragma unroll
            for (int ct = 0; ct < 4; ct++) {
                bf16x8 wfrag = *(const bf16x8*)&s.n.wf[((ct * 8 + ks) * 64 + l) * 8];
                acc[ct] = __builtin_amdgcn_mfma_f32_32x32x16_bf16(wfrag, af[ks], acc[ct], 0, 0, 0);
            }
        }

        // ---- h1 pack ----
        unsigned P[4][4][2], Q[4][4][2];
#pragma unroll
        for (int ct = 0; ct < 4; ct++) {
#pragma unroll
            for (int g = 0; g < 4; g++) {
                float4 bv = *(const float4*)&s.n.cv[32 * ct + 8 * g + 4 * hi];
                float h0  = fmaxf(acc[ct][4 * g + 0] + bv.x, 0.f);
                float h1v = fmaxf(acc[ct][4 * g + 1] + bv.y, 0.f);
                float h2v = fmaxf(acc[ct][4 * g + 2] + bv.z, 0.f);
                float h3v = fmaxf(acc[ct][4 * g + 3] + bv.w, 0.f);
                P[ct][g][0] = pack2(h0, h1v);
                P[ct][g][1] = pack2(h2v, h3v);
            }
        }
#pragma unroll
        for (int ct = 0; ct < 4; ct++)
#pragma unroll
            for (int g = 0; g < 4; g++)
#pragma unroll
                for (int p = 0; p < 2; p++)
                    Q[ct][g][p] = (unsigned)__shfl_xor((int)P[ct][g][p], 32, 64);

        __syncthreads();   // all waves done reading wf(W1)

        // ---- W2 transform ----
#pragma unroll
        for (int t = 0; t < 4; t++) {
            int rem = t * 512 + tid;
            int lv = rem & 63, ks = (rem >> 6) & 7, ct = rem >> 9;
            int k0 = ks * 16 + 8 * (lv >> 5);
            int n  = ct * 32 + (lv & 31);
            bf16x8 wvv;
#pragma unroll
            for (int j = 0; j < 8; j++) wvv[j] = f2bf(W2[(k0 + j) * HDIM + n]);
            *(bf16x8*)&s.n.wf[rem * 8] = wvv;
        }
        __syncthreads();   // wf(W2) ready

        // ---- layer 2 ----
        f32x16 acc2[4];
#pragma unroll
        for (int ct = 0; ct < 4; ct++) acc2[ct] = zz;
#pragma unroll
        for (int ks2 = 0; ks2 < 8; ks2++) {
            const int c  = ks2 >> 1;
            const int s2 = (ks2 & 1) * 2;
            union { bf16x8 v; unsigned u[4]; } bb;
            bb.u[0] = hi ? Q[c][s2 + 1][0] : P[c][s2][0];
            bb.u[1] = hi ? Q[c][s2 + 1][1] : P[c][s2][1];
            bb.u[2] = hi ? P[c][s2 + 1][0] : Q[c][s2][0];
            bb.u[3] = hi ? P[c][s2 + 1][1] : Q[c][s2][1];
#pragma unroll
            for (int ct = 0; ct < 4; ct++) {
                bf16x8 wfrag = *(const bf16x8*)&s.n.wf[((ct * 8 + ks2) * 64 + l) * 8];
                acc2[ct] = __builtin_amdgcn_mfma_f32_32x32x16_bf16(wfrag, bb.v, acc2[ct], 0, 0, 0);
            }
        }

        // ---- epilogue ----
        float pq = 0.f, pk = 0.f;
#pragma unroll
        for (int ct = 0; ct < 4; ct++) {
#pragma unroll
            for (int g = 0; g < 4; g++) {
                float4 b2v = *(const float4*)&s.n.cv[128 + 32 * ct + 8 * g + 4 * hi];
                float4 wqv = *(const float4*)&s.n.cv[256 + 32 * ct + 8 * g + 4 * hi];
                float4 wkv = *(const float4*)&s.n.cv[384 + 32 * ct + 8 * g + 4 * hi];
                const float* b2a = (const float*)&b2v;
                const float* wqa = (const float*)&wqv;
                const float* wka = (const float*)&wkv;
#pragma unroll
                for (int i = 0; i < 4; i++) {
                    float hv = fmaxf(acc2[ct][4 * g + i] + b2a[i], 0.f);
                    pq = fmaf(hv, wqa[i], pq);
                    pk = fmaf(hv, wka[i], pk);
                }
            }
        }
        pq += __shfl_xor(pq, 32, 64);
        pk += __shfl_xor(pk, 32, 64);
        if (hi == 0 && node < N) atomicExch(&tab[node], pack2(pq, pk));
    } else {
        // ========== pure-cast block: stream casts for i in [0, CS) ==========
        const int rank = blk - NB;
        const int4* ein4c = (const int4*)ein;
        float4* o4 = (float4*)out;
        for (int i = rank * 512 + tid; i < CS; i += NC * 512) {
            int4 v = ein4c[i];
            o4[2 * U + i] = make_float4((float)v.x, (float)v.y, (float)v.z, (float)v.w);
            int4 w = ein4c[U + i];
            o4[3 * U + i] = make_float4((float)w.x, (float)w.y, (float)w.z, (float)w.w);
        }
    }

    __threadfence();
    cg::this_grid().sync();   // all tab writes device-visible

    // ================= phase E: edge scores (R14 512-thr body) =============
    const int wv = tid >> 6, ln = tid & 63;      // 8 waves

    // ---- staging DMA: 10240 uint4 = 8 waves x 20 iters ----
    const uint4* tg4 = (const uint4*)tab;
#pragma unroll
    for (int t = 0; t < LIM / 4 / 512; t++) {
        int c = (t * 8 + wv) * 64;
        __builtin_amdgcn_global_load_lds(
            (const __attribute__((address_space(1))) void*)(tg4 + c + ln),
            (__attribute__((address_space(3))) void*)((char*)s.lt + (size_t)c * 16),
            16, 0, 0);
    }
    __builtin_amdgcn_sched_barrier(0);

    const int chunk = (U + (int)gridDim.x - 1) / (int)gridDim.x;
    const int ustart = blk * chunk;
    const int uend = min(U, ustart + chunk);

    const int4* eip4 = (const int4*)eip;
    const int4* ein4 = (const int4*)ein;
    float4* out4 = (float4*)out;

    // ---- phase A: preload all ein, write casts (u >= CS only) ----
    const int u0 = ustart + tid;
    int4 ns[4], nd[4];
    bool vv[4];
#pragma unroll
    for (int i = 0; i < 4; i++) {
        int u = u0 + i * 512;
        vv[i] = u < uend;
        ns[i] = make_int4(0, 0, 0, 0);
        nd[i] = make_int4(0, 0, 0, 0);
        if (vv[i]) {
            ns[i] = ein4[u]; nd[i] = ein4[U + u];
            if (u >= CS) {
                out4[2 * U + u] = make_float4((float)ns[i].x, (float)ns[i].y,
                                              (float)ns[i].z, (float)ns[i].w);
                out4[3 * U + u] = make_float4((float)nd[i].x, (float)nd[i].y,
                                              (float)nd[i].z, (float)nd[i].w);
            }
        }
    }
    int4 ps = {0,0,0,0}, pd = {0,0,0,0};
    if (vv[0]) { ps = eip4[u0]; pd = eip4[U + u0]; }

    __syncthreads();   // drains DMA (vmcnt); lt visible

    const float be = be_p[0];
#define GATHER(i) ((i) < LIM ? s.lt[i] : tab[i])
#define SCORE(us, ud) (__uint_as_float((us) << 16) + __uint_as_float((ud) & 0xFFFF0000u) + be)
#pragma unroll
    for (int i = 0; i < 4; i++) {
        const int u = u0 + i * 512;
        int4 psn = {0,0,0,0}, pdn = {0,0,0,0};
        if (i < 3 && vv[i + 1]) { psn = eip4[u + 512]; pdn = eip4[U + u + 512]; }
        if (vv[i]) {
            unsigned a0 = GATHER(ps.x), a1 = GATHER(ps.y), a2 = GATHER(ps.z), a3 = GATHER(ps.w);
            unsigned b0 = GATHER(pd.x), b1 = GATHER(pd.y), b2 = GATHER(pd.z), b3 = GATHER(pd.w);
            out4[u] = make_float4(SCORE(a0, b0), SCORE(a1, b1), SCORE(a2, b2), SCORE(a3, b3));
            unsigned c0 = GATHER(ns[i].x), c1 = GATHER(ns[i].y),
                     c2 = GATHER(ns[i].z), c3 = GATHER(ns[i].w);
            unsigned d0 = GATHER(nd[i].x), d1 = GATHER(nd[i].y),
                     d2 = GATHER(nd[i].z), d3 = GATHER(nd[i].w);
            out4[U + u] = make_float4(SCORE(c0, d0), SCORE(c1, d1), SCORE(c2, d2), SCORE(c3, d3));
        }
        ps = psn; pd = pdn;
    }
#undef GATHER
#undef SCORE
}

extern "C" void kernel_launch(void* const* d_in, const int* in_sizes, int n_in,
                              void* d_out, int out_size, void* d_ws, size_t ws_size,
                              hipStream_t stream) {
    const float* x   = (const float*)d_in[0];
    const int*   eip = (const int*)d_in[1];
    const int*   ein = (const int*)d_in[2];
    // d_in[3] = batch (unused)
    const float* W1  = (const float*)d_in[4];
    const float* b1  = (const float*)d_in[5];
    const float* W2  = (const float*)d_in[6];
    const float* b2  = (const float*)d_in[7];
    const float* We  = (const float*)d_in[8];
    const float* be  = (const float*)d_in[9];

    int N = in_sizes[0] / CDIM;
    int E = in_sizes[1] / 2;

    unsigned* tab = (unsigned*)d_ws;   // N*4 B packed bf16x2 score table
    float* outp = (float*)d_out;

    void* args[] = { (void*)&x, (void*)&eip, (void*)&ein,
                     (void*)&W1, (void*)&b1, (void*)&W2, (void*)&b2,
                     (void*)&We, (void*)&be, (void*)&tab, (void*)&outp,
                     (void*)&N, (void*)&E };
    hipLaunchCooperativeKernel((const void*)fused_kernel, dim3(256), dim3(512),
                               args, 0, stream);
}

// Round 21
// 29.386 us; speedup vs baseline: 5.4119x; 3.8722x over previous
//
#include <hip/hip_runtime.h>

#define CDIM 128
#define HDIM 128
#define LIM  40960   // nodes cached in edge LDS (x4 B = 163840 B = full 160 KiB)

typedef short bf16x8 __attribute__((ext_vector_type(8)));
typedef float f32x16 __attribute__((ext_vector_type(16)));

// fp32 -> bf16 bits, round-to-nearest-even
static __device__ __forceinline__ short f2bf(float f) {
    union { float f; unsigned u; } v; v.f = f;
    unsigned r = v.u + 0x7FFFu + ((v.u >> 16) & 1u);
    return (short)(r >> 16);
}
static __device__ __forceinline__ unsigned pack2(float a, float b) {
    return (unsigned)(unsigned short)f2bf(a) | ((unsigned)(unsigned short)f2bf(b) << 16);
}

// ---------------------------------------------------------------------------
// K1: grid = 256 blocks x 512 thr.
//   blocks < NB  : R17 node body verbatim (256 nodes/block, one-layer LDS).
//   blocks >= NB : pure cast streamers for i in [0, CS) — uses the 60 CUs
//                  and ~half-idle HBM BW of the node window. Static partition,
//                  no atomics, no cooperative launch (R20 lesson: coop costs
//                  ~100 us fixed on this harness).
// ---------------------------------------------------------------------------
__global__ __launch_bounds__(512) void node_mfma(
    const float* __restrict__ x,
    const float* __restrict__ W1, const float* __restrict__ b1,
    const float* __restrict__ W2, const float* __restrict__ b2,
    const float* __restrict__ We, const int* __restrict__ ein,
    unsigned* __restrict__ tab, float* __restrict__ out,
    int N, int E, int CS)
{
    __shared__ __align__(16) short wf[16384];   // 32 KB: ONE layer
    __shared__ __align__(16) float cv[512];     // b1 | b2 | Wq | Wk

    const int tid = threadIdx.x;
    const int blk = blockIdx.x;
    const int NB  = (N + 255) >> 8;             // node blocks (196)
    const int U   = E >> 2;

    if (blk >= NB) {
        // ---- pure cast streamer: out[2E+..] = float(ein[..]), i < CS ----
        const int NC = (int)gridDim.x - NB;     // 60 blocks
        const int4* ein4 = (const int4*)ein;
        float4* o4 = (float4*)out;
        for (int i = (blk - NB) * 512 + tid; i < CS; i += NC * 512) {
            int4 v = ein4[i];
            o4[2 * U + i] = make_float4((float)v.x, (float)v.y, (float)v.z, (float)v.w);
            int4 w = ein4[U + i];
            o4[3 * U + i] = make_float4((float)w.x, (float)w.y, (float)w.z, (float)w.w);
        }
        return;
    }

    const int l   = tid & 63;
    const int col = l & 31;
    const int hi  = l >> 5;
    const int node = blk * 256 + (tid >> 6) * 32 + col;

    // ---- issue ALL x loads first (latency hides under W1 transform) ----
    const int nclamp = (node < N) ? node : (N - 1);
    const float* xb = &x[(size_t)nclamp * CDIM + hi * 8];
    float4 xr[16];
#pragma unroll
    for (int ks = 0; ks < 8; ks++) {
        xr[2 * ks]     = *(const float4*)(xb + ks * 16);
        xr[2 * ks + 1] = *(const float4*)(xb + ks * 16 + 4);
    }

    // ---- W1 transform: dest-linear, 1 ds_write_b128/iter, 4 iters/thread ----
#pragma unroll
    for (int t = 0; t < 4; t++) {
        int rem = t * 512 + tid;                 // 0..2047
        int lv = rem & 63, ks = (rem >> 6) & 7, ct = rem >> 9;
        int k0 = ks * 16 + 8 * (lv >> 5);
        int n  = ct * 32 + (lv & 31);
        bf16x8 wv;
#pragma unroll
        for (int j = 0; j < 8; j++) wv[j] = f2bf(W1[(k0 + j) * HDIM + n]);
        *(bf16x8*)&wf[rem * 8] = wv;
    }
    cv[tid] = (tid < 128) ? b1[tid] : (tid < 256) ? b2[tid - 128] : We[tid - 256];

    // ---- convert x to bf16 fragments ----
    bf16x8 af[8];
#pragma unroll
    for (int ks = 0; ks < 8; ks++) {
        float4 v0 = xr[2 * ks], v1 = xr[2 * ks + 1];
        af[ks][0] = f2bf(v0.x); af[ks][1] = f2bf(v0.y);
        af[ks][2] = f2bf(v0.z); af[ks][3] = f2bf(v0.w);
        af[ks][4] = f2bf(v1.x); af[ks][5] = f2bf(v1.y);
        af[ks][6] = f2bf(v1.z); af[ks][7] = f2bf(v1.w);
    }
    __syncthreads();   // wf(W1) + cv ready

    const f32x16 zz = {0.f,0.f,0.f,0.f,0.f,0.f,0.f,0.f,0.f,0.f,0.f,0.f,0.f,0.f,0.f,0.f};

    // ---- layer 1: A = W1-frag (LDS, lane-linear), B = x^T-frag (regs) ----
    f32x16 acc[4];
#pragma unroll
    for (int ct = 0; ct < 4; ct++) acc[ct] = zz;
#pragma unroll
    for (int ks = 0; ks < 8; ks++) {
#pragma unroll
        for (int ct = 0; ct < 4; ct++) {
            bf16x8 wfrag = *(const bf16x8*)&wf[((ct * 8 + ks) * 64 + l) * 8];
            acc[ct] = __builtin_amdgcn_mfma_f32_32x32x16_bf16(wfrag, af[ks], acc[ct], 0, 0, 0);
        }
    }

    // ---- h1 = relu(D1 + b1): pack own 64 features as bf16 pairs ----
    unsigned P[4][4][2], Q[4][4][2];
#pragma unroll
    for (int ct = 0; ct < 4; ct++) {
#pragma unroll
        for (int g = 0; g < 4; g++) {
            float4 bv = *(const float4*)&cv[32 * ct + 8 * g + 4 * hi];
            float h0  = fmaxf(acc[ct][4 * g + 0] + bv.x, 0.f);
            float h1v = fmaxf(acc[ct][4 * g + 1] + bv.y, 0.f);
            float h2v = fmaxf(acc[ct][4 * g + 2] + bv.z, 0.f);
            float h3v = fmaxf(acc[ct][4 * g + 3] + bv.w, 0.f);
            P[ct][g][0] = pack2(h0, h1v);
            P[ct][g][1] = pack2(h2v, h3v);
        }
    }
#pragma unroll
    for (int ct = 0; ct < 4; ct++)
#pragma unroll
        for (int g = 0; g < 4; g++)
#pragma unroll
            for (int p = 0; p < 2; p++)
                Q[ct][g][p] = (unsigned)__shfl_xor((int)P[ct][g][p], 32, 64);

    __syncthreads();   // all waves done reading wf(W1)

    // ---- W2 transform into the same buffer ----
#pragma unroll
    for (int t = 0; t < 4; t++) {
        int rem = t * 512 + tid;
        int lv = rem & 63, ks = (rem >> 6) & 7, ct = rem >> 9;
        int k0 = ks * 16 + 8 * (lv >> 5);
        int n  = ct * 32 + (lv & 31);
        bf16x8 wv;
#pragma unroll
        for (int j = 0; j < 8; j++) wv[j] = f2bf(W2[(k0 + j) * HDIM + n]);
        *(bf16x8*)&wf[rem * 8] = wv;
    }
    __syncthreads();   // wf(W2) ready

    // ---- layer 2: B2 frag in-register; A = W2-frag from LDS ----
    f32x16 acc2[4];
#pragma unroll
    for (int ct = 0; ct < 4; ct++) acc2[ct] = zz;
#pragma unroll
    for (int ks2 = 0; ks2 < 8; ks2++) {
        const int c  = ks2 >> 1;
        const int s2 = (ks2 & 1) * 2;
        union { bf16x8 v; unsigned u[4]; } bb;
        bb.u[0] = hi ? Q[c][s2 + 1][0] : P[c][s2][0];
        bb.u[1] = hi ? Q[c][s2 + 1][1] : P[c][s2][1];
        bb.u[2] = hi ? P[c][s2 + 1][0] : Q[c][s2][0];
        bb.u[3] = hi ? P[c][s2 + 1][1] : Q[c][s2][1];
#pragma unroll
        for (int ct = 0; ct < 4; ct++) {
            bf16x8 wfrag = *(const bf16x8*)&wf[((ct * 8 + ks2) * 64 + l) * 8];
            acc2[ct] = __builtin_amdgcn_mfma_f32_32x32x16_bf16(wfrag, bb.v, acc2[ct], 0, 0, 0);
        }
    }

    // ---- epilogue: partial dot over own 64 n2, combine across lane pair ----
    float pq = 0.f, pk = 0.f;
#pragma unroll
    for (int ct = 0; ct < 4; ct++) {
#pragma unroll
        for (int g = 0; g < 4; g++) {
            float4 b2v = *(const float4*)&cv[128 + 32 * ct + 8 * g + 4 * hi];
            float4 wqv = *(const float4*)&cv[256 + 32 * ct + 8 * g + 4 * hi];
            float4 wkv = *(const float4*)&cv[384 + 32 * ct + 8 * g + 4 * hi];
            const float* b2a = (const float*)&b2v;
            const float* wqa = (const float*)&wqv;
            const float* wka = (const float*)&wkv;
#pragma unroll
            for (int i = 0; i < 4; i++) {
                float hv = fmaxf(acc2[ct][4 * g + i] + b2a[i], 0.f);
                pq = fmaf(hv, wqa[i], pq);
                pk = fmaf(hv, wka[i], pk);
            }
        }
    }
    pq += __shfl_xor(pq, 32, 64);
    pk += __shfl_xor(pk, 32, 64);
    if (hi == 0 && node < N) tab[node] = pack2(pq, pk);
}

// ---------------------------------------------------------------------------
// K2: edge pass (R18 verbatim + cast guard u >= CS).
// ---------------------------------------------------------------------------
__global__ __launch_bounds__(1024) void edge_kernel(
    const int* __restrict__ eip, const int* __restrict__ ein,
    const unsigned* __restrict__ tab, const float* __restrict__ be_p,
    float* __restrict__ out, int E, int CS)
{
    __shared__ __align__(16) unsigned lt[LIM];   // 163840 B
    const int tid = threadIdx.x;
    const int wv = tid >> 6, ln = tid & 63;

    const int U = E >> 2;                         // 4-edge units (E % 4 == 0)
    const int chunk = (U + gridDim.x - 1) / gridDim.x;
    const int ustart = blockIdx.x * chunk;
    const int uend = min(U, ustart + chunk);

    const int4* eip4 = (const int4*)eip;
    const int4* ein4 = (const int4*)ein;
    float4* out4 = (float4*)out;

    const int u0 = ustart + tid, u1 = u0 + 1024;
    const bool v0 = u0 < uend, v1 = u1 < uend;

    // ---- step 1: issue index preloads (oldest in the vmcnt FIFO) ----
    int4 ns0 = {0,0,0,0}, nd0 = {0,0,0,0}, ns1 = {0,0,0,0}, nd1 = {0,0,0,0};
    int4 ps0 = {0,0,0,0}, pd0 = {0,0,0,0};
    if (v0) { ns0 = ein4[u0]; nd0 = ein4[U + u0]; ps0 = eip4[u0]; pd0 = eip4[U + u0]; }
    if (v1) { ns1 = ein4[u1]; nd1 = ein4[U + u1]; }
    __builtin_amdgcn_sched_barrier(0);   // pin: index loads issue before DMA

    // ---- step 2: issue staging DMA: 10240 uint4, 16 waves x 10 iters ----
    const uint4* tg4 = (const uint4*)tab;
#pragma unroll
    for (int t = 0; t < LIM / 4 / 1024; t++) {
        int c = (t * 16 + wv) * 64;
        __builtin_amdgcn_global_load_lds(
            (const __attribute__((address_space(1))) void*)(tg4 + c + ln),
            (__attribute__((address_space(3))) void*)((char*)lt + (size_t)c * 16),
            16, 0, 0);
    }
    __builtin_amdgcn_sched_barrier(0);   // pin: DMA issued before cast waits

    // ---- step 3: cast outputs for u >= CS ([0,CS) written by K1) ----
    if (v0 && u0 >= CS) {
        out4[2 * U + u0] = make_float4((float)ns0.x, (float)ns0.y, (float)ns0.z, (float)ns0.w);
        out4[3 * U + u0] = make_float4((float)nd0.x, (float)nd0.y, (float)nd0.z, (float)nd0.w);
    }
    if (v1 && u1 >= CS) {
        out4[2 * U + u1] = make_float4((float)ns1.x, (float)ns1.y, (float)ns1.z, (float)ns1.w);
        out4[3 * U + u1] = make_float4((float)nd1.x, (float)nd1.y, (float)nd1.z, (float)nd1.w);
    }
    __syncthreads();   // drains DMA (vmcnt 0) + makes lt visible

    const float be = be_p[0];
#define GATHER(i) ((i) < LIM ? lt[i] : tab[i])
#define SCORE(us, ud) (__uint_as_float((us) << 16) + __uint_as_float((ud) & 0xFFFF0000u) + be)

    // ---- phase B: u1's eip loads issue first, hidden under u0's work ----
    int4 ps1 = {0,0,0,0}, pd1 = {0,0,0,0};
    if (v1) { ps1 = eip4[u1]; pd1 = eip4[U + u1]; }

    if (v0) {
        unsigned a0 = GATHER(ps0.x), a1 = GATHER(ps0.y), a2 = GATHER(ps0.z), a3 = GATHER(ps0.w);
        unsigned b0 = GATHER(pd0.x), b1 = GATHER(pd0.y), b2 = GATHER(pd0.z), b3 = GATHER(pd0.w);
        out4[u0] = make_float4(SCORE(a0,b0), SCORE(a1,b1), SCORE(a2,b2), SCORE(a3,b3));
        unsigned c0 = GATHER(ns0.x), c1 = GATHER(ns0.y), c2 = GATHER(ns0.z), c3 = GATHER(ns0.w);
        unsigned d0 = GATHER(nd0.x), d1 = GATHER(nd0.y), d2 = GATHER(nd0.z), d3 = GATHER(nd0.w);
        out4[U + u0] = make_float4(SCORE(c0,d0), SCORE(c1,d1), SCORE(c2,d2), SCORE(c3,d3));
    }
    if (v1) {
        unsigned a0 = GATHER(ps1.x), a1 = GATHER(ps1.y), a2 = GATHER(ps1.z), a3 = GATHER(ps1.w);
        unsigned b0 = GATHER(pd1.x), b1 = GATHER(pd1.y), b2 = GATHER(pd1.z), b3 = GATHER(pd1.w);
        out4[u1] = make_float4(SCORE(a0,b0), SCORE(a1,b1), SCORE(a2,b2), SCORE(a3,b3));
        unsigned c0 = GATHER(ns1.x), c1 = GATHER(ns1.y), c2 = GATHER(ns1.z), c3 = GATHER(ns1.w);
        unsigned d0 = GATHER(nd1.x), d1 = GATHER(nd1.y), d2 = GATHER(nd1.z), d3 = GATHER(nd1.w);
        out4[U + u1] = make_float4(SCORE(c0,d0), SCORE(c1,d1), SCORE(c2,d2), SCORE(c3,d3));
    }
#undef GATHER
#undef SCORE
}

extern "C" void kernel_launch(void* const* d_in, const int* in_sizes, int n_in,
                              void* d_out, int out_size, void* d_ws, size_t ws_size,
                              hipStream_t stream) {
    const float* x   = (const float*)d_in[0];
    const int*   eip = (const int*)d_in[1];
    const int*   ein = (const int*)d_in[2];
    // d_in[3] = batch (unused)
    const float* W1  = (const float*)d_in[4];
    const float* b1  = (const float*)d_in[5];
    const float* W2  = (const float*)d_in[6];
    const float* b2  = (const float*)d_in[7];
    const float* We  = (const float*)d_in[8];
    const float* be  = (const float*)d_in[9];

    const int N = in_sizes[0] / CDIM;
    const int E = in_sizes[1] / 2;
    const int U = E >> 2;
    const int CS = (U * 2) / 5;        // cast slice handled by K1's idle CUs

    unsigned* tab = (unsigned*)d_ws;   // N*4 B packed bf16x2 score table

    node_mfma<<<256, 512, 0, stream>>>(x, W1, b1, W2, b2, We, ein, tab,
                                       (float*)d_out, N, E, CS);
    edge_kernel<<<256, 1024, 0, stream>>>(eip, ein, tab, be, (float*)d_out, E, CS);
}

// Round 22
// 28.458 us; speedup vs baseline: 5.5885x; 1.0326x over previous
//
#include <hip/hip_runtime.h>

#define CDIM 128
#define HDIM 128
#define LIM  40960   // nodes cached in edge LDS (x4 B = 163840 B = full 160 KiB)

typedef short bf16x8 __attribute__((ext_vector_type(8)));
typedef float f32x16 __attribute__((ext_vector_type(16)));

// fp32 -> bf16 bits, round-to-nearest-even
static __device__ __forceinline__ short f2bf(float f) {
    union { float f; unsigned u; } v; v.f = f;
    unsigned r = v.u + 0x7FFFu + ((v.u >> 16) & 1u);
    return (short)(r >> 16);
}
static __device__ __forceinline__ unsigned pack2(float a, float b) {
    return (unsigned)(unsigned short)f2bf(a) | ((unsigned)(unsigned short)f2bf(b) << 16);
}

// ---------------------------------------------------------------------------
// K1: node MLP -> bf16x2 score table (R17/R18 structure — best measured).
// 256 nodes/block (512 thr), one-layer LDS (34.8 KB, 4 blocks/CU), W2
// restaged mid-kernel. No launch-bounds occupancy clamp (R15 lesson: a
// min-waves arg below the body's ~88-VGPR need forces spills).
// ---------------------------------------------------------------------------
__global__ __launch_bounds__(512) void node_mfma(
    const float* __restrict__ x,
    const float* __restrict__ W1, const float* __restrict__ b1,
    const float* __restrict__ W2, const float* __restrict__ b2,
    const float* __restrict__ We,
    unsigned* __restrict__ tab, int N)
{
    __shared__ __align__(16) short wf[16384];   // 32 KB: ONE layer
    __shared__ __align__(16) float cv[512];     // b1 | b2 | Wq | Wk

    const int tid = threadIdx.x;
    const int l   = tid & 63;
    const int col = l & 31;
    const int hi  = l >> 5;
    const int node = blockIdx.x * 256 + (tid >> 6) * 32 + col;

    // ---- issue ALL x loads first (latency hides under W1 transform) ----
    const int nclamp = (node < N) ? node : (N - 1);
    const float* xb = &x[(size_t)nclamp * CDIM + hi * 8];
    float4 xr[16];
#pragma unroll
    for (int ks = 0; ks < 8; ks++) {
        xr[2 * ks]     = *(const float4*)(xb + ks * 16);
        xr[2 * ks + 1] = *(const float4*)(xb + ks * 16 + 4);
    }

    // ---- W1 transform: dest-linear, 1 ds_write_b128/iter, 4 iters/thread ----
#pragma unroll
    for (int t = 0; t < 4; t++) {
        int rem = t * 512 + tid;                 // 0..2047
        int lv = rem & 63, ks = (rem >> 6) & 7, ct = rem >> 9;
        int k0 = ks * 16 + 8 * (lv >> 5);
        int n  = ct * 32 + (lv & 31);
        bf16x8 wv;
#pragma unroll
        for (int j = 0; j < 8; j++) wv[j] = f2bf(W1[(k0 + j) * HDIM + n]);
        *(bf16x8*)&wf[rem * 8] = wv;
    }
    if (tid < 512)
        cv[tid] = (tid < 128) ? b1[tid] : (tid < 256) ? b2[tid - 128] : We[tid - 256];

    // ---- convert x to bf16 fragments ----
    bf16x8 af[8];
#pragma unroll
    for (int ks = 0; ks < 8; ks++) {
        float4 v0 = xr[2 * ks], v1 = xr[2 * ks + 1];
        af[ks][0] = f2bf(v0.x); af[ks][1] = f2bf(v0.y);
        af[ks][2] = f2bf(v0.z); af[ks][3] = f2bf(v0.w);
        af[ks][4] = f2bf(v1.x); af[ks][5] = f2bf(v1.y);
        af[ks][6] = f2bf(v1.z); af[ks][7] = f2bf(v1.w);
    }
    __syncthreads();   // wf(W1) + cv ready

    const f32x16 zz = {0.f,0.f,0.f,0.f,0.f,0.f,0.f,0.f,0.f,0.f,0.f,0.f,0.f,0.f,0.f,0.f};

    // ---- layer 1: A = W1-frag (LDS, lane-linear), B = x^T-frag (regs) ----
    f32x16 acc[4];
#pragma unroll
    for (int ct = 0; ct < 4; ct++) acc[ct] = zz;
#pragma unroll
    for (int ks = 0; ks < 8; ks++) {
#pragma unroll
        for (int ct = 0; ct < 4; ct++) {
            bf16x8 wfrag = *(const bf16x8*)&wf[((ct * 8 + ks) * 64 + l) * 8];
            acc[ct] = __builtin_amdgcn_mfma_f32_32x32x16_bf16(wfrag, af[ks], acc[ct], 0, 0, 0);
        }
    }

    // ---- h1 = relu(D1 + b1): pack own 64 features as bf16 pairs ----
    unsigned P[4][4][2], Q[4][4][2];
#pragma unroll
    for (int ct = 0; ct < 4; ct++) {
#pragma unroll
        for (int g = 0; g < 4; g++) {
            float4 bv = *(const float4*)&cv[32 * ct + 8 * g + 4 * hi];
            float h0  = fmaxf(acc[ct][4 * g + 0] + bv.x, 0.f);
            float h1v = fmaxf(acc[ct][4 * g + 1] + bv.y, 0.f);
            float h2v = fmaxf(acc[ct][4 * g + 2] + bv.z, 0.f);
            float h3v = fmaxf(acc[ct][4 * g + 3] + bv.w, 0.f);
            P[ct][g][0] = pack2(h0, h1v);
            P[ct][g][1] = pack2(h2v, h3v);
        }
    }
#pragma unroll
    for (int ct = 0; ct < 4; ct++)
#pragma unroll
        for (int g = 0; g < 4; g++)
#pragma unroll
            for (int p = 0; p < 2; p++)
                Q[ct][g][p] = (unsigned)__shfl_xor((int)P[ct][g][p], 32, 64);

    __syncthreads();   // all waves done reading wf(W1)

    // ---- W2 transform into the same buffer ----
#pragma unroll
    for (int t = 0; t < 4; t++) {
        int rem = t * 512 + tid;
        int lv = rem & 63, ks = (rem >> 6) & 7, ct = rem >> 9;
        int k0 = ks * 16 + 8 * (lv >> 5);
        int n  = ct * 32 + (lv & 31);
        bf16x8 wv;
#pragma unroll
        for (int j = 0; j < 8; j++) wv[j] = f2bf(W2[(k0 + j) * HDIM + n]);
        *(bf16x8*)&wf[rem * 8] = wv;
    }
    __syncthreads();   // wf(W2) ready

    // ---- layer 2: B2 frag in-register; A = W2-frag from LDS ----
    f32x16 acc2[4];
#pragma unroll
    for (int ct = 0; ct < 4; ct++) acc2[ct] = zz;
#pragma unroll
    for (int ks2 = 0; ks2 < 8; ks2++) {
        const int c  = ks2 >> 1;
        const int s2 = (ks2 & 1) * 2;
        union { bf16x8 v; unsigned u[4]; } bb;
        bb.u[0] = hi ? Q[c][s2 + 1][0] : P[c][s2][0];
        bb.u[1] = hi ? Q[c][s2 + 1][1] : P[c][s2][1];
        bb.u[2] = hi ? P[c][s2 + 1][0] : Q[c][s2][0];
        bb.u[3] = hi ? P[c][s2 + 1][1] : Q[c][s2][1];
#pragma unroll
        for (int ct = 0; ct < 4; ct++) {
            bf16x8 wfrag = *(const bf16x8*)&wf[((ct * 8 + ks2) * 64 + l) * 8];
            acc2[ct] = __builtin_amdgcn_mfma_f32_32x32x16_bf16(wfrag, bb.v, acc2[ct], 0, 0, 0);
        }
    }

    // ---- epilogue: partial dot over own 64 n2, combine across lane pair ----
    float pq = 0.f, pk = 0.f;
#pragma unroll
    for (int ct = 0; ct < 4; ct++) {
#pragma unroll
        for (int g = 0; g < 4; g++) {
            float4 b2v = *(const float4*)&cv[128 + 32 * ct + 8 * g + 4 * hi];
            float4 wqv = *(const float4*)&cv[256 + 32 * ct + 8 * g + 4 * hi];
            float4 wkv = *(const float4*)&cv[384 + 32 * ct + 8 * g + 4 * hi];
            const float* b2a = (const float*)&b2v;
            const float* wqa = (const float*)&wqv;
            const float* wka = (const float*)&wkv;
#pragma unroll
            for (int i = 0; i < 4; i++) {
                float hv = fmaxf(acc2[ct][4 * g + i] + b2a[i], 0.f);
                pq = fmaf(hv, wqa[i], pq);
                pk = fmaf(hv, wka[i], pk);
            }
        }
    }
    pq += __shfl_xor(pq, 32, 64);
    pk += __shfl_xor(pk, 32, 64);
    if (hi == 0 && node < N) tab[node] = pack2(pq, pk);
}

// ---------------------------------------------------------------------------
// K2: edge pass (R18 verbatim — best measured). FIFO-vmcnt-aware issue order:
// index preloads before the staging DMA; casts computed mid-DMA; phase B
// carries ein + eip(u0), loads eip(u1) under u0's work.
// ---------------------------------------------------------------------------
__global__ __launch_bounds__(1024) void edge_kernel(
    const int* __restrict__ eip, const int* __restrict__ ein,
    const unsigned* __restrict__ tab, const float* __restrict__ be_p,
    float* __restrict__ out, int E)
{
    __shared__ __align__(16) unsigned lt[LIM];   // 163840 B
    const int tid = threadIdx.x;
    const int wv = tid >> 6, ln = tid & 63;

    const int U = E >> 2;                         // 4-edge units (E % 4 == 0)
    const int chunk = (U + gridDim.x - 1) / gridDim.x;
    const int ustart = blockIdx.x * chunk;
    const int uend = min(U, ustart + chunk);

    const int4* eip4 = (const int4*)eip;
    const int4* ein4 = (const int4*)ein;
    float4* out4 = (float4*)out;

    const int u0 = ustart + tid, u1 = u0 + 1024;
    const bool v0 = u0 < uend, v1 = u1 < uend;

    // ---- step 1: issue index preloads (OLDEST in the vmcnt FIFO) ----
    int4 ns0 = {0,0,0,0}, nd0 = {0,0,0,0}, ns1 = {0,0,0,0}, nd1 = {0,0,0,0};
    int4 ps0 = {0,0,0,0}, pd0 = {0,0,0,0};
    if (v0) { ns0 = ein4[u0]; nd0 = ein4[U + u0]; ps0 = eip4[u0]; pd0 = eip4[U + u0]; }
    if (v1) { ns1 = ein4[u1]; nd1 = ein4[U + u1]; }
    __builtin_amdgcn_sched_barrier(0);   // pin: index loads issue before DMA

    // ---- step 2: issue staging DMA: 10240 uint4, 16 waves x 10 iters ----
    const uint4* tg4 = (const uint4*)tab;
#pragma unroll
    for (int t = 0; t < LIM / 4 / 1024; t++) {
        int c = (t * 16 + wv) * 64;
        __builtin_amdgcn_global_load_lds(
            (const __attribute__((address_space(1))) void*)(tg4 + c + ln),
            (__attribute__((address_space(3))) void*)((char*)lt + (size_t)c * 16),
            16, 0, 0);
    }
    __builtin_amdgcn_sched_barrier(0);   // pin: DMA issued before cast waits

    // ---- step 3: cast outputs — indices complete at vmcnt(10), mid-DMA ----
    if (v0) {
        out4[2 * U + u0] = make_float4((float)ns0.x, (float)ns0.y, (float)ns0.z, (float)ns0.w);
        out4[3 * U + u0] = make_float4((float)nd0.x, (float)nd0.y, (float)nd0.z, (float)nd0.w);
    }
    if (v1) {
        out4[2 * U + u1] = make_float4((float)ns1.x, (float)ns1.y, (float)ns1.z, (float)ns1.w);
        out4[3 * U + u1] = make_float4((float)nd1.x, (float)nd1.y, (float)nd1.z, (float)nd1.w);
    }
    __syncthreads();   // drains DMA (vmcnt 0) + makes lt visible

    const float be = be_p[0];
#define GATHER(i) ((i) < LIM ? lt[i] : tab[i])
#define SCORE(us, ud) (__uint_as_float((us) << 16) + __uint_as_float((ud) & 0xFFFF0000u) + be)

    // ---- phase B: u1's eip loads issue first, hidden under u0's work ----
    int4 ps1 = {0,0,0,0}, pd1 = {0,0,0,0};
    if (v1) { ps1 = eip4[u1]; pd1 = eip4[U + u1]; }

    if (v0) {
        unsigned a0 = GATHER(ps0.x), a1 = GATHER(ps0.y), a2 = GATHER(ps0.z), a3 = GATHER(ps0.w);
        unsigned b0 = GATHER(pd0.x), b1 = GATHER(pd0.y), b2 = GATHER(pd0.z), b3 = GATHER(pd0.w);
        out4[u0] = make_float4(SCORE(a0,b0), SCORE(a1,b1), SCORE(a2,b2), SCORE(a3,b3));
        unsigned c0 = GATHER(ns0.x), c1 = GATHER(ns0.y), c2 = GATHER(ns0.z), c3 = GATHER(ns0.w);
        unsigned d0 = GATHER(nd0.x), d1 = GATHER(nd0.y), d2 = GATHER(nd0.z), d3 = GATHER(nd0.w);
        out4[U + u0] = make_float4(SCORE(c0,d0), SCORE(c1,d1), SCORE(c2,d2), SCORE(c3,d3));
    }
    if (v1) {
        unsigned a0 = GATHER(ps1.x), a1 = GATHER(ps1.y), a2 = GATHER(ps1.z), a3 = GATHER(ps1.w);
        unsigned b0 = GATHER(pd1.x), b1 = GATHER(pd1.y), b2 = GATHER(pd1.z), b3 = GATHER(pd1.w);
        out4[u1] = make_float4(SCORE(a0,b0), SCORE(a1,b1), SCORE(a2,b2), SCORE(a3,b3));
        unsigned c0 = GATHER(ns1.x), c1 = GATHER(ns1.y), c2 = GATHER(ns1.z), c3 = GATHER(ns1.w);
        unsigned d0 = GATHER(nd1.x), d1 = GATHER(nd1.y), d2 = GATHER(nd1.z), d3 = GATHER(nd1.w);
        out4[U + u1] = make_float4(SCORE(c0,d0), SCORE(c1,d1), SCORE(c2,d2), SCORE(c3,d3));
    }
#undef GATHER
#undef SCORE
}

extern "C" void kernel_launch(void* const* d_in, const int* in_sizes, int n_in,
                              void* d_out, int out_size, void* d_ws, size_t ws_size,
                              hipStream_t stream) {
    const float* x   = (const float*)d_in[0];
    const int*   eip = (const int*)d_in[1];
    const int*   ein = (const int*)d_in[2];
    // d_in[3] = batch (unused)
    const float* W1  = (const float*)d_in[4];
    const float* b1  = (const float*)d_in[5];
    const float* W2  = (const float*)d_in[6];
    const float* b2  = (const float*)d_in[7];
    const float* We  = (const float*)d_in[8];
    const float* be  = (const float*)d_in[9];

    const int N = in_sizes[0] / CDIM;
    const int E = in_sizes[1] / 2;

    unsigned* tab = (unsigned*)d_ws;   // N*4 B packed bf16x2 score table

    node_mfma<<<(N + 255) / 256, 512, 0, stream>>>(x, W1, b1, W2, b2, We, tab, N);
    edge_kernel<<<256, 1024, 0, stream>>>(eip, ein, tab, be, (float*)d_out, E);
}